// Round 1
// baseline (6200.793 us; speedup 1.0000x reference)
//
#include <hip/hip_runtime.h>
#include <cstdint>
#include <cstddef>

#define CIN   16
#define T_DIM 31
#define H_DIM 128
#define W_DIM 128
#define OC    32
#define CHID  16
#define TH    16
#define TW    16

__device__ __forceinline__ float sigmoid_f(float x) {
  return 1.0f / (1.0f + __expf(-x));
}
__device__ __forceinline__ float tanh_f(float x) {
  // tanh(x) = 2*sigmoid(2x) - 1 ; saturates correctly for large |x|
  return 2.0f / (1.0f + __expf(-2.0f * x)) - 1.0f;
}

__global__ __launch_bounds__(256, 1)
void qrnn3d_fused(const float* __restrict__ in, const float* __restrict__ Wg,
                  const float* __restrict__ bg, float* __restrict__ out) {
  // LDS ring: 3 time-slices, each [CIN][TH+2][TW+2] with halo. 62,208 B.
  __shared__ float xs[3][CIN][TH + 2][TW + 2];

  const int tid  = threadIdx.x;
  const int bid  = blockIdx.x;
  const int b    = bid >> 6;          // 4 batches
  const int tile = bid & 63;          // 8x8 tiles of 16x16
  const int h0   = (tile >> 3) << 4;
  const int w0   = (tile & 7) << 4;
  const int ph   = tid >> 4, pw = tid & 15;
  const int gh   = h0 + ph, gw = w0 + pw;

  // --- slice loader: fills one [CIN][18][18] slab (zero-padded at edges) ---
  auto load_slice = [&](float* dst, int tz) {
    const int SL = CIN * 18 * 18;  // 5184
    if (tz < 0 || tz >= T_DIM) {
      for (int i = tid; i < SL; i += 256) dst[i] = 0.0f;
    } else {
      for (int i = tid; i < SL; i += 256) {
        int ci = i / 324;
        int r  = i - ci * 324;
        int hh = r / 18;
        int ww = r - hh * 18;
        int ih = h0 + hh - 1, iw = w0 + ww - 1;
        float v = 0.0f;
        if ((unsigned)ih < (unsigned)H_DIM && (unsigned)iw < (unsigned)W_DIM)
          v = in[(((size_t)(b * CIN + ci) * T_DIM + tz) * H_DIM + ih) * W_DIM + iw];
        dst[i] = v;
      }
    }
  };

  // preload tz = -1, 0, 1 into slots 0, 1, 2
  load_slice(&xs[0][0][0][0], -1);
  load_slice(&xs[1][0][0][0], 0);
  load_slice(&xs[2][0][0][0], 1);
  __syncthreads();

  float hstate[CHID];
#pragma unroll
  for (int c = 0; c < CHID; ++c) hstate[c] = 0.0f;

  int s0 = 0, s1 = 1, s2 = 2;  // slots for tz = t-1, t, t+1
  const int xoff = ph * (TW + 2) + pw;

  for (int t = 0; t < T_DIM; ++t) {
    float acc[OC];
#pragma unroll
    for (int oc = 0; oc < OC; ++oc) acc[oc] = bg[oc];

    const float* sl[3] = { &xs[s0][0][0][0], &xs[s1][0][0][0], &xs[s2][0][0][0] };

#pragma unroll 1
    for (int ci = 0; ci < CIN; ++ci) {
      // stage this ci's 27-neighborhood in registers (ds_read_b32 w/ imm offsets)
      float xv[27];
#pragma unroll
      for (int kd = 0; kd < 3; ++kd) {
        const float* sp = sl[kd] + ci * 324 + xoff;
#pragma unroll
        for (int kh = 0; kh < 3; ++kh)
#pragma unroll
          for (int kw = 0; kw < 3; ++kw)
            xv[kd * 9 + kh * 3 + kw] = sp[kh * (TW + 2) + kw];
      }
      // weights: block-uniform, contiguous 27-float rows -> scalar loads
#pragma unroll 4
      for (int oc = 0; oc < OC; ++oc) {
        const float* wr = Wg + (oc * CIN + ci) * 27;
#pragma unroll
        for (int k = 0; k < 27; ++k)
          acc[oc] = fmaf(xv[k], wr[k], acc[oc]);
      }
    }

    // activations + fo-pool recurrence + store
#pragma unroll
    for (int c = 0; c < CHID; ++c) {
      float z  = tanh_f(acc[c]);
      float f  = sigmoid_f(acc[c + CHID]);
      float hv = f * hstate[c] + (1.0f - f) * z;
      hstate[c] = hv;
      out[(((size_t)(b * CHID + c) * T_DIM + t) * H_DIM + gh) * W_DIM + gw] = hv;
    }

    __syncthreads();
    if (t < T_DIM - 1) load_slice(&xs[s0][0][0][0], t + 2);  // tz=t+2 -> old s0 slot
    __syncthreads();
    int tmp = s0; s0 = s1; s1 = s2; s2 = tmp;
  }
}

extern "C" void kernel_launch(void* const* d_in, const int* in_sizes, int n_in,
                              void* d_out, int out_size, void* d_ws, size_t ws_size,
                              hipStream_t stream) {
  const float* in = (const float*)d_in[0];
  const float* Wg = (const float*)d_in[1];
  const float* bg = (const float*)d_in[2];
  float* out      = (float*)d_out;
  (void)in_sizes; (void)n_in; (void)out_size; (void)d_ws; (void)ws_size;
  qrnn3d_fused<<<dim3(256), dim3(256), 0, stream>>>(in, Wg, bg, out);
}

// Round 2
// 134.343 us; speedup vs baseline: 46.1565x; 46.1565x over previous
//
#include <hip/hip_runtime.h>
#include <cstdint>
#include <cstddef>

#define CIN    16
#define T_DIM  31
#define H_DIM  128
#define W_DIM  128
#define CHID   16
#define TILE_H 8
#define TILE_W 32
#define SH     (TILE_H + 2)   // 10
#define SW     (TILE_W + 2)   // 34
#define SLICE  (SH * SW * CIN)  // 5440 shorts
#define NPAIR  (SLICE / 2)      // 2720
#define CH_STRIDE 507904        // 31*128*128

typedef short bf16x8 __attribute__((ext_vector_type(8)));
typedef float f32x16 __attribute__((ext_vector_type(16)));

__device__ __forceinline__ unsigned bf16_bits(float x) {
  unsigned u = __builtin_bit_cast(unsigned, x);
  u += 0x7FFFu + ((u >> 16) & 1u);   // RTNE
  return u >> 16;
}

__global__ __launch_bounds__(256, 1)
void qrnn3d_mfma(const float* __restrict__ in, const float* __restrict__ Wg,
                 const float* __restrict__ bg, float* __restrict__ out) {
  __shared__ short xs[3][SLICE];

  const int tid  = threadIdx.x;
  const int bid  = blockIdx.x;
  const int b    = bid >> 6;
  const int tile = bid & 63;
  const int th   = tile >> 2;          // 16 h-tiles
  const int tw   = tile & 3;           // 4 w-tiles
  const int h0   = th * TILE_H, w0 = tw * TILE_W;

  const int lane = tid & 63;
  const int wid  = tid >> 6;           // wave 0..3
  const int col  = lane & 31;          // N position (w offset)
  const int half = lane >> 5;          // ci half

  // ---- weights -> 27 A-frags in registers (one-time; L2-cached) ----
  bf16x8 wfrag[27];
#pragma unroll
  for (int tau = 0; tau < 27; ++tau) {
    bf16x8 f;
#pragma unroll
    for (int j = 0; j < 8; ++j) {
      float wv = Wg[col * 432 + (half * 8 + j) * 27 + tau];
      f[j] = (short)bf16_bits(wv);
    }
    wfrag[tau] = f;
  }

  // per-lane bias for its 8 z/f channel pairs
  float bzv[8], bfv[8];
  int   ocoff[8];  // output-channel offset (elements) for stores
#pragma unroll
  for (int r = 0; r < 8; ++r) {
    int oc = (r & 3) + 8 * (r >> 2) + 4 * half;   // 0..15
    bzv[r] = bg[oc];
    bfv[r] = bg[oc + 16];
    ocoff[r] = oc * CH_STRIDE;
  }

  // ---- staging (fp32 global -> regs -> bf16 LDS, ci-pair packed) ----
  float slo[11], shi[11];
  auto stage_load = [&](int tz) {
#pragma unroll
    for (int i = 0; i < 11; ++i) {
      int p = tid + i * 256;
      float lo = 0.f, hi = 0.f;
      if (p < NPAIR) {
        int ci2 = p / 340;
        int rem = p - ci2 * 340;
        int hh  = rem / 34;
        int ww  = rem - hh * 34;
        int gh = h0 + hh - 1, gw = w0 + ww - 1;
        if ((unsigned)gh < (unsigned)H_DIM && (unsigned)gw < (unsigned)W_DIM &&
            (unsigned)tz < (unsigned)T_DIM) {
          size_t base = (((size_t)(b * CIN + ci2 * 2) * T_DIM + tz) * H_DIM + gh) * W_DIM + gw;
          lo = in[base];
          hi = in[base + CH_STRIDE];
        }
      }
      slo[i] = lo; shi[i] = hi;
    }
  };
  auto stage_store = [&](short* dst) {
#pragma unroll
    for (int i = 0; i < 11; ++i) {
      int p = tid + i * 256;
      if (p < NPAIR) {
        int ci2 = p / 340;
        int rem = p - ci2 * 340;
        int hh  = rem / 34;
        int ww  = rem - hh * 34;
        unsigned u = (bf16_bits(slo[i]) & 0xFFFFu) | (bf16_bits(shi[i]) << 16);
        *(unsigned*)(dst + (hh * 34 + ww) * 16 + ci2 * 2) = u;
      }
    }
  };

  // prologue: slot0 = zeros (slice t=-1), slot1 = slice 0, slot2 = slice 1
  {
    unsigned* z = (unsigned*)&xs[0][0];
    for (int i = tid; i < NPAIR; i += 256) z[i] = 0u;
    stage_load(0); stage_store(&xs[1][0]);
    stage_load(1); stage_store(&xs[2][0]);
  }
  __syncthreads();

  short* p0 = &xs[0][0];  // slice t-1
  short* p1 = &xs[1][0];  // slice t
  short* p2 = &xs[2][0];  // slice t+1

  const int hh0 = wid;        // two row-tiles per wave
  const int hh1 = wid + 4;
  const int tb0 = (hh0 * 34 + col) * 16 + half * 8;
  const int tb1 = (hh1 * 34 + col) * 16 + half * 8;

  float hst0[8], hst1[8];
#pragma unroll
  for (int r = 0; r < 8; ++r) { hst0[r] = 0.f; hst1[r] = 0.f; }

  const size_t obase = (size_t)(b * CHID) * CH_STRIDE + (size_t)h0 * W_DIM + w0 + col;

  for (int t = 0; t < T_DIM; ++t) {
    if (t < 30) stage_load(t + 2);   // issue HBM loads early

    f32x16 acc0, acc1;
#pragma unroll
    for (int i = 0; i < 16; ++i) { acc0[i] = 0.f; acc1[i] = 0.f; }

    const short* sp[3] = { p0, p1, p2 };
#pragma unroll
    for (int kd = 0; kd < 3; ++kd) {
      const short* bA = sp[kd] + tb0;
      const short* bB = sp[kd] + tb1;
#pragma unroll
      for (int kh = 0; kh < 3; ++kh) {
#pragma unroll
        for (int kw = 0; kw < 3; ++kw) {
          const int off = (kh * 34 + kw) * 16;
          const int tau = kd * 9 + kh * 3 + kw;
          bf16x8 f0 = *(const bf16x8*)(bA + off);
          bf16x8 f1 = *(const bf16x8*)(bB + off);
          acc0 = __builtin_amdgcn_mfma_f32_32x32x16_bf16(wfrag[tau], f0, acc0, 0, 0, 0);
          acc1 = __builtin_amdgcn_mfma_f32_32x32x16_bf16(wfrag[tau], f1, acc1, 0, 0, 0);
        }
      }
    }

    // activations + fo-pool + stores (register-only)
    const size_t ot = obase + (size_t)t * (H_DIM * W_DIM);
#pragma unroll
    for (int r = 0; r < 8; ++r) {
      {
        float zg = acc0[r] + bzv[r];
        float fg = acc0[r + 8] + bfv[r];
        zg = 1.0f - 2.0f / (expf(2.0f * zg) + 1.0f);
        fg = 1.0f / (1.0f + expf(-fg));
        float h = fg * hst0[r] + (1.0f - fg) * zg;
        hst0[r] = h;
        out[ot + ocoff[r] + hh0 * W_DIM] = h;
      }
      {
        float zg = acc1[r] + bzv[r];
        float fg = acc1[r + 8] + bfv[r];
        zg = 1.0f - 2.0f / (expf(2.0f * zg) + 1.0f);
        fg = 1.0f / (1.0f + expf(-fg));
        float h = fg * hst1[r] + (1.0f - fg) * zg;
        hst1[r] = h;
        out[ot + ocoff[r] + hh1 * W_DIM] = h;
      }
    }

    if (t < 30) {
      __syncthreads();
      stage_store(p0);          // slice t+2 overwrites slice t-1 slot
      __syncthreads();
      short* tmp = p0; p0 = p1; p1 = p2; p2 = tmp;
    }
  }
}

extern "C" void kernel_launch(void* const* d_in, const int* in_sizes, int n_in,
                              void* d_out, int out_size, void* d_ws, size_t ws_size,
                              hipStream_t stream) {
  const float* in = (const float*)d_in[0];
  const float* Wg = (const float*)d_in[1];
  const float* bg = (const float*)d_in[2];
  float* out      = (float*)d_out;
  (void)in_sizes; (void)n_in; (void)out_size; (void)d_ws; (void)ws_size;
  qrnn3d_mfma<<<dim3(256), dim3(256), 0, stream>>>(in, Wg, bg, out);
}